// Round 9
// baseline (3899.397 us; speedup 1.0000x reference)
//
#include <hip/hip_runtime.h>
#include <math.h>

#define HD 128
#define LW 32
#define VOCABN 200000
#define NLEAF 2048
#define NPAR 2047
#define NNODE 4095
#define MAXC 4
#define NCLASS 4
#define SCALE 0.08838834764831845f  // 1/sqrt(128)

// Workspace layout (floats), compile-time offsets => k_seq needs ONE base ptr
#define OFF_XE   0
#define OFF_NODE 524160    // + NNODE*HD
#define OFF_W3   786304    // + NLEAF*HD
#define OFF_WQ   851840    // + 512*HD
#define OFF_AZ   1113856   // + NPAR*HD
#define OFF_AR   1375872
#define OFF_AH   1637888
#define OFF_PREV 1899904
#define OFF_ES   2685952   // + NPAR*384
#define OFF_HG   2688000   // unused by k_seq now; layout kept stable
#define OFF_HTR  2688128
#define OFF_ET   2688256
#define WS_END   (OFF_ET + (size_t)VOCABN * HD)

// LDS-only barrier: lgkmcnt(0) makes ds_writes visible, does NOT drain vmcnt
// (prefetch global loads stay in flight across it).
#define BARL() asm volatile("s_waitcnt lgkmcnt(0)\n\ts_barrier" ::: "memory")
// Pin float4 into VGPRs component-wise (keep-alive; exact round-3 scheme).
#define PIN4(v) asm volatile("" : "+v"((v).x), "+v"((v).y), "+v"((v).z), "+v"((v).w))
#define LD4(p, k) (*(const float4*)((p) + 4 * (k)))

#define PIN_ALL() do { PIN4(A0); PIN4(A1); PIN4(A2); PIN4(A3); \
    PIN4(A4); PIN4(A5); PIN4(A6); PIN4(A7); PIN4(A8); PIN4(A9); \
    PIN4(A10); PIN4(A11); PIN4(A12); PIN4(A13); PIN4(A14); PIN4(A15); } while (0)

#define RL(x, j) __int_as_float(__builtin_amdgcn_readlane((x), (j)))

// ROUND-9 CHANGE (only change vs round 3, best = 3236 us): readlane batching.
// Old CH2 issued 4 v_readlane (VALU writes SGPR) immediately followed by FMAs
// READING those SGPRs -- the gfx9-lineage VALU-write-SGPR->VALU-read hazard
// inserts wait states on every RL->FMA adjacency (32 per matvec per wave).
// G16 issues 16 independent readlanes back-to-back (distinct SGPRs, no
// hazard), then 32 FMAs whose SGPR operands are >=16 instructions old --
// outside the hazard window. Per-accumulator FP order unchanged (a0 sees
// W0,W1,W2,W3 terms in order; b0 sees W4..W7): bit-exact vs round 3.
// Weight sourcing settled by R7 (LDS: worse) / R8 (resident: neutral):
// L2-streamed plain loads are fully hidden -> keep round 3's path.
#define G16(W0, W1, W2, W3_, W4, W5, W6, W7, XS, J) { \
    float t0_=RL(XS,(J)+0),  t1_=RL(XS,(J)+1),  t2_=RL(XS,(J)+2),  t3_=RL(XS,(J)+3), \
          t4_=RL(XS,(J)+4),  t5_=RL(XS,(J)+5),  t6_=RL(XS,(J)+6),  t7_=RL(XS,(J)+7), \
          t8_=RL(XS,(J)+8),  t9_=RL(XS,(J)+9),  tA_=RL(XS,(J)+10), tB_=RL(XS,(J)+11), \
          tC_=RL(XS,(J)+12), tD_=RL(XS,(J)+13), tE_=RL(XS,(J)+14), tF_=RL(XS,(J)+15); \
    a0 += (W0).x*t0_ + (W0).y*t1_;   a1 += (W0).z*t2_ + (W0).w*t3_; \
    b0 += (W4).x*t0_ + (W4).y*t1_;   b1 += (W4).z*t2_ + (W4).w*t3_; \
    a0 += (W1).x*t4_ + (W1).y*t5_;   a1 += (W1).z*t6_ + (W1).w*t7_; \
    b0 += (W5).x*t4_ + (W5).y*t5_;   b1 += (W5).z*t6_ + (W5).w*t7_; \
    a0 += (W2).x*t8_ + (W2).y*t9_;   a1 += (W2).z*tA_ + (W2).w*tB_; \
    b0 += (W6).x*t8_ + (W6).y*t9_;   b1 += (W6).z*tA_ + (W6).w*tB_; \
    a0 += (W3_).x*tC_ + (W3_).y*tD_; a1 += (W3_).z*tE_ + (W3_).w*tF_; \
    b0 += (W7).x*tC_ + (W7).y*tD_;   b1 += (W7).z*tE_ + (W7).w*tF_; }

// 2-row x 32-K matvec: two 16-RL batches, 64 FMA total. Same readlane
// indices (BASE..BASE+31) and accumulation order as round 3.
#define MATVEC2(XS, BASE) do { \
    G16(A0, A1, A2, A3, A8,  A9,  A10, A11, XS, (BASE)); \
    G16(A4, A5, A6, A7, A12, A13, A14, A15, XS, (BASE) + 16); } while (0)

// ---------------------------------------------------------------------------
// Kernel 1a (fallback): xe via uncoalesced gather
// ---------------------------------------------------------------------------
__global__ void k_xe(const float* __restrict__ xw, const int* __restrict__ xi,
                     const float* __restrict__ E, float* __restrict__ xe) {
    int n = blockIdx.x;
    int h = threadIdx.x;
    __shared__ int   sidx[LW];
    __shared__ float sw[LW];
    if (h < LW) { sidx[h] = xi[n * LW + h]; sw[h] = xw[n * LW + h]; }
    __syncthreads();
    float acc = 0.f;
#pragma unroll
    for (int l = 0; l < LW; ++l)
        acc += E[(size_t)h * VOCABN + sidx[l]] * sw[l];
    xe[(size_t)n * HD + h] = acc;
}

// ---------------------------------------------------------------------------
// Kernel 1b: transpose E (H x VOCAB) -> ET (VOCAB x H)
// ---------------------------------------------------------------------------
__global__ void k_transpose(const float* __restrict__ E, float* __restrict__ ET) {
    __shared__ float tile[32][33];
    int vb = blockIdx.x * 32, hb = blockIdx.y * 32;
    int tx = threadIdx.x, ty = threadIdx.y;  // 32 x 8
#pragma unroll
    for (int r = 0; r < 32; r += 8)
        tile[ty + r][tx] = E[(size_t)(hb + ty + r) * VOCABN + vb + tx];
    __syncthreads();
#pragma unroll
    for (int r = 0; r < 32; r += 8)
        ET[(size_t)(vb + ty + r) * HD + hb + tx] = tile[tx][ty + r];
}

// Kernel 1c: coalesced gather+reduce from ET.
__global__ void k_xe_t(const float* __restrict__ xw, const int* __restrict__ xi,
                       const float* __restrict__ ET, float* __restrict__ xe) {
    int n = blockIdx.x;
    int h = threadIdx.x;
    __shared__ int   sidx[LW];
    __shared__ float sw[LW];
    if (h < LW) { sidx[h] = xi[n * LW + h]; sw[h] = xw[n * LW + h]; }
    __syncthreads();
    float acc = 0.f;
#pragma unroll
    for (int l = 0; l < LW; ++l)
        acc += ET[(size_t)sidx[l] * HD + h] * sw[l];
    xe[(size_t)n * HD + h] = acc;
}

// ---------------------------------------------------------------------------
// Kernel 2: leaf cells -> node_h[0:NLEAF]
// ---------------------------------------------------------------------------
__global__ void k_leaf(const float* __restrict__ xe, const float* __restrict__ Wz,
                       const float* __restrict__ bz, const float* __restrict__ Wh,
                       const float* __restrict__ bh, float* __restrict__ node_h) {
    int n = blockIdx.x;
    int j = threadIdx.x;
    __shared__ float xl[HD];
    xl[j] = xe[(size_t)n * HD + j];
    __syncthreads();
    float az = bz[j], ah = bh[j];
    const float* wzr = Wz + (size_t)j * HD;
    const float* whr = Wh + (size_t)j * HD;
#pragma unroll 4
    for (int k = 0; k < HD; ++k) { az += wzr[k] * xl[k]; ah += whr[k] * xl[k]; }
    float z = 1.f / (1.f + expf(-az));
    float c = tanhf(ah);
    node_h[(size_t)n * HD + j] = (1.f - z) * c;
}

// ---------------------------------------------------------------------------
// Kernel 3: fused weight stack W3 (512 x 128):
//   rows 0..127: WV^T / 128..255: U_z WV^T / 256..383: U_r WV^T / 384..511: U_h
// ---------------------------------------------------------------------------
__global__ void k_fuse(const float* __restrict__ WV, const float* __restrict__ Uz,
                       const float* __restrict__ Ur, const float* __restrict__ Uh,
                       float* __restrict__ w3) {
    int r = blockIdx.x;
    int b = threadIdx.x;
    float v;
    if (r < 128) {
        v = WV[(size_t)b * HD + r];
    } else if (r < 384) {
        const float* u  = (r < 256 ? Uz + (size_t)(r - 128) * HD : Ur + (size_t)(r - 256) * HD);
        const float* wv = WV + (size_t)b * HD;
        float a = 0.f;
#pragma unroll 4
        for (int j = 0; j < HD; ++j) a += u[j] * wv[j];
        v = a;
    } else {
        v = Uh[(size_t)(r - 384) * HD + b];
    }
    w3[(size_t)r * HD + b] = v;
}

// ---------------------------------------------------------------------------
// Kernel 4: per-parent precompute
// ---------------------------------------------------------------------------
__global__ void k_ppre(const float* __restrict__ xe, const float* __restrict__ WQ,
                       const float* __restrict__ WK, const float* __restrict__ Wz,
                       const float* __restrict__ bz, const float* __restrict__ Wr,
                       const float* __restrict__ br, const float* __restrict__ Wh,
                       const float* __restrict__ bh, float* __restrict__ wq,
                       float* __restrict__ az, float* __restrict__ ar,
                       float* __restrict__ ah) {
    int i = blockIdx.x;
    int j = threadIdx.x;
    __shared__ float xl[HD], ql[HD];
    xl[j] = xe[(size_t)(NLEAF + i) * HD + j];
    __syncthreads();
    float q = 0.f;
#pragma unroll 4
    for (int h = 0; h < HD; ++h) q += xl[h] * WQ[(size_t)h * HD + j];
    ql[j] = 1.f / (1.f + expf(-q));
    __syncthreads();
    float w = 0.f;
#pragma unroll 4
    for (int k = 0; k < HD; ++k) w += WK[(size_t)j * HD + k] * ql[k];
    wq[(size_t)i * HD + j] = w;
    float vz = bz[j], vr = br[j], vh = bh[j];
#pragma unroll 4
    for (int k = 0; k < HD; ++k) {
        float xv = xl[k];
        vz += Wz[(size_t)j * HD + k] * xv;
        vr += Wr[(size_t)j * HD + k] * xv;
        vh += Wh[(size_t)j * HD + k] * xv;
    }
    az[(size_t)i * HD + j] = vz;
    ar[(size_t)i * HD + j] = vr;
    ah[(size_t)i * HD + j] = vh;
}

// ---------------------------------------------------------------------------
// Kernel 5: aggregated leaf-child precompute per parent
// ---------------------------------------------------------------------------
__global__ void k_chpre(const int* __restrict__ tree, const float* __restrict__ node_h,
                        const float* __restrict__ w3, const float* __restrict__ wq_all,
                        float* __restrict__ preVexp, float* __restrict__ expsum) {
    int i = blockIdx.x;
    int j = threadIdx.x;
    __shared__ float hl[HD];
    __shared__ float red[HD];
    float wqj = wq_all[(size_t)i * HD + j];
    float acc0 = 0.f, acc1 = 0.f, acc2 = 0.f, esum = 0.f;
    for (int c = 0; c < MAXC; ++c) {
        int child = tree[i * MAXC + c];
        if (child < 0 || child >= NLEAF) continue;  // uniform per block
        __syncthreads();
        hl[j] = node_h[(size_t)child * HD + j];
        __syncthreads();
        red[j] = hl[j] * wqj;
        __syncthreads();
        for (int s = 64; s > 0; s >>= 1) {
            if (j < s) red[j] += red[j + s];
            __syncthreads();
        }
        float e = expf(red[0] * SCALE);
        float d0 = 0.f, d1 = 0.f, d2 = 0.f;
#pragma unroll 4
        for (int k = 0; k < HD; ++k) {
            float x = hl[k];
            d0 += w3[(size_t)j * HD + k] * x;
            d1 += w3[(size_t)(128 + j) * HD + k] * x;
            d2 += w3[(size_t)(256 + j) * HD + k] * x;
        }
        acc0 += e * d0; acc1 += e * d1; acc2 += e * d2; esum += e;
    }
    preVexp[(size_t)i * 384 + j]       = acc0;
    preVexp[(size_t)i * 384 + 128 + j] = acc1;
    preVexp[(size_t)i * 384 + 256 + j] = acc2;
    if (j == 0) expsum[i] = esum;
}

// ---------------------------------------------------------------------------
// Kernel 6: sequential chain. 1024 threads (16 waves, 4/EU). Structure is
// EXACT round 3 (best verified: 3236 us): lane-local h, no global stores /
// dcache_inv / vmcnt drains; gates only on the 4 P3 waves; 3 phases /
// 3 LDS-only barriers per step. ONLY change: G16 readlane batching (see
// macro comment) to kill the VALU-writes-SGPR -> VALU-reads-SGPR hazard
// on every RL->FMA adjacency.
// Wave roles (wave w, SIMD = w&3):
//   w<12 (P1): K-chunk c1=w&3, row-group g1=w>>2; rows 128g1+l, 128g1+64+l
//   w>=12 (P3): K-chunk c3=w-12; U_h rows l, 64+l; gates for m3=64*(c3>>1)+l
// ---------------------------------------------------------------------------
__global__ __launch_bounds__(1024)
__attribute__((amdgpu_waves_per_eu(4, 4)))
void k_seq(float* __restrict__ ws, const float* __restrict__ Wout,
           const float* __restrict__ bout, const float* __restrict__ y,
           float* __restrict__ out) {
    const int t  = threadIdx.x;
    const int l  = t & 63;
    const int w  = t >> 6;               // wave 0..15
    const bool isP1 = (w < 12);
    // P1 mapping
    const int c1 = w & 3;                // K-chunk (32 floats)
    const int g1 = w >> 2;               // row group 0..2
    const int r0 = 128 * g1 + l;         // rows r0 and r0+64
    // P3 mapping
    const int w12 = w - 12;
    const int c3  = w12 & 3;             // K-chunk
    const int q3  = c3 >> 1;             // m-half
    const int m3  = 64 * q3 + l;         // elementwise lane (P3 only)

    __shared__ float part1[4 * 384];     // [chunk][row]
    __shared__ float part3[4 * 128];     // [chunk][row]
    __shared__ float red[HD];            // h*wq products (for next score)
    __shared__ float sS;                 // reduced chain score * SCALE
    __shared__ float h_lds[HD];
    __shared__ float outv[NCLASS];

    // ---- weights: 16 pinned float4 per thread (2 rows x 32-K chunk) ----
    const int woff = isP1 ? (r0 * HD + 32 * c1)
                          : ((384 + l) * HD + 32 * c3);
    const float* wp0 = ws + OFF_W3 + woff;
    const float* wp1 = wp0 + 64 * HD;    // row +64
    float4 A0 = LD4(wp0, 0), A1 = LD4(wp0, 1), A2 = LD4(wp0, 2), A3 = LD4(wp0, 3),
           A4 = LD4(wp0, 4), A5 = LD4(wp0, 5), A6 = LD4(wp0, 6), A7 = LD4(wp0, 7),
           A8 = LD4(wp1, 0), A9 = LD4(wp1, 1), A10 = LD4(wp1, 2), A11 = LD4(wp1, 3),
           A12 = LD4(wp1, 4), A13 = LD4(wp1, 5), A14 = LD4(wp1, 6), A15 = LD4(wp1, 7);
    PIN_ALL();

    // ---- prefetch registers (P3 waves only; element m3) ----
    float pv0 = 0.f, pv1 = 0.f, pv2 = 0.f, paz = 0.f, par = 0.f, pah = 0.f,
          pwq = 0.f, pes = 0.f;
    if (!isP1) {
        pv0 = ws[OFF_PREV + m3];       pv1 = ws[OFF_PREV + 128 + m3];
        pv2 = ws[OFF_PREV + 256 + m3];
        paz = ws[OFF_AZ + m3];         par = ws[OFF_AR + m3];
        pah = ws[OFF_AH + m3];
        pes = ws[OFF_ES];
        pwq = ws[OFF_WQ + HD + m3];    // wq[1], consumed in phase C of step 0
    }
    if (t < HD) {
        h_lds[t] = 0.f;                          // h_{-1} = 0
        red[t]   = (t < 64) ? -1e30f : 0.f;      // step 0: no chain child
    }
    __syncthreads();

    float zreg = 0.f, htvreg = 0.f;

    for (int i = 0; i < NPAR; ++i) {
        const int inext = (i + 1 < NPAR) ? i + 1 : NPAR - 1;
        const int in2   = (i + 2 < NPAR) ? i + 2 : NPAR - 1;

        PIN_ALL();

        // ---- Phase A: P1 matvec. h fetched via ONE per-lane ds_read with
        //      half-wave duplication so readlane indices are literal 0..31.
        //      Wave 12 reduces the chain score concurrently. ----
        if (isP1) {
            const int hx = __float_as_int(h_lds[32 * c1 + (l & 31)]);
            float a0 = 0.f, a1 = 0.f, b0 = 0.f, b1 = 0.f;
            MATVEC2(hx, 0);
            part1[c1 * 384 + r0]      = a0 + a1;
            part1[c1 * 384 + r0 + 64] = b0 + b1;
        } else if (w12 == 0) {
            float s = red[l] + red[l + 64];
#pragma unroll
            for (int o = 32; o > 0; o >>= 1) s += __shfl_down(s, o, 64);
            if (l == 0) sS = s * SCALE;
        }
        BARL();

        // ---- Phase B: P3 waves only: gates for element m3, then 2x32 U_h
        //      matvec on htr (in-lane; readlane base picked by chunk half) ----
        if (!isP1) {
            float e   = expf(sS);
            float vd  = part1[m3]        + part1[384 + m3]
                      + part1[768 + m3]  + part1[1152 + m3];
            float zd  = part1[128 + m3]  + part1[512 + m3]
                      + part1[896 + m3]  + part1[1280 + m3];
            float rd  = part1[256 + m3]  + part1[640 + m3]
                      + part1[1024 + m3] + part1[1408 + m3];
            float inv = 1.f / (pes + e);
            float htv = (pv0 + e * vd) * inv;
            float z   = 1.f / (1.f + expf(-(paz + (pv1 + e * zd) * inv)));
            float rr  = 1.f / (1.f + expf(-(par + (pv2 + e * rd) * inv)));
            float htr = htv * rr;
            zreg = z; htvreg = htv;
            const int xh = __float_as_int(htr);
            float a0 = 0.f, a1 = 0.f, b0 = 0.f, b1 = 0.f;
            if ((c3 & 1) == 0) { MATVEC2(xh, 0); } else { MATVEC2(xh, 32); }
            part3[c3 * 128 + l]      = a0 + a1;
            part3[c3 * 128 + l + 64] = b0 + b1;
        }
        BARL();

        // ---- Phase C: P3 waves: finalize h[m3]; publish h + score products;
        //      refill prefetches (fire-and-forget) ----
        if (!isP1) {
            float u  = part3[m3]       + part3[128 + m3]
                     + part3[256 + m3] + part3[384 + m3];
            float c  = tanhf(pah + u);
            float hv = zreg * htvreg + (1.f - zreg) * c;
            if ((w12 & 1) == 0) {       // one wave per half: w12=0 (q0), 2 (q1)
                h_lds[m3] = hv;
                red[m3]   = hv * pwq;   // <h_i, wq_{i+1}> products
            }
            pv0 = ws[OFF_PREV + inext * 384 + m3];
            pv1 = ws[OFF_PREV + inext * 384 + 128 + m3];
            pv2 = ws[OFF_PREV + inext * 384 + 256 + m3];
            paz = ws[OFF_AZ + inext * HD + m3];
            par = ws[OFF_AR + inext * HD + m3];
            pah = ws[OFF_AH + inext * HD + m3];
            pes = ws[OFF_ES + inext];
            pwq = ws[OFF_WQ + in2 * HD + m3];
        }
        BARL();
    }

    // ---- output head (h_lds holds h_{NPAR-1}) ----
    if (t < NCLASS) {
        float acc = bout[t];
#pragma unroll 4
        for (int k = 0; k < HD; ++k) acc += Wout[(size_t)t * HD + k] * h_lds[k];
        outv[t] = acc;
    }
    __syncthreads();
    if (t == 0) {
        float mx = fmaxf(fmaxf(outv[0], outv[1]), fmaxf(outv[2], outv[3]));
        float e0 = expf(outv[0] - mx), e1 = expf(outv[1] - mx);
        float e2 = expf(outv[2] - mx), e3 = expf(outv[3] - mx);
        float inv = 1.f / (e0 + e1 + e2 + e3);
        float p0 = e0 * inv, p1 = e1 * inv, p2 = e2 * inv, p3 = e3 * inv;
        out[0] = p0; out[1] = p1; out[2] = p2; out[3] = p3;
        float d0 = y[0] - p0, d1 = y[1] - p1, d2 = y[2] - p2, d3 = y[3] - p3;
        out[4] = d0 * d0 + d1 * d1 + d2 * d2 + d3 * d3;
    }
}

// ---------------------------------------------------------------------------
extern "C" void kernel_launch(void* const* d_in, const int* in_sizes, int n_in,
                              void* d_out, int out_size, void* d_ws, size_t ws_size,
                              hipStream_t stream) {
    const float* x_word  = (const float*)d_in[0];
    const int*   x_index = (const int*)d_in[1];
    const int*   tree    = (const int*)d_in[2];
    const float* y       = (const float*)d_in[3];
    const float* E_bu    = (const float*)d_in[4];
    const float* WQ      = (const float*)d_in[5];
    const float* WK      = (const float*)d_in[6];
    const float* WV      = (const float*)d_in[7];
    const float* W_z     = (const float*)d_in[8];
    const float* U_z     = (const float*)d_in[9];
    const float* b_z     = (const float*)d_in[10];
    const float* W_r     = (const float*)d_in[11];
    const float* U_r     = (const float*)d_in[12];
    const float* b_r     = (const float*)d_in[13];
    const float* W_h     = (const float*)d_in[14];
    const float* U_h     = (const float*)d_in[15];
    const float* b_h     = (const float*)d_in[16];
    const float* W_out   = (const float*)d_in[17];
    const float* b_out   = (const float*)d_in[18];

    float* ws      = (float*)d_ws;
    float* xe      = ws + OFF_XE;
    float* node_h  = ws + OFF_NODE;
    float* w3      = ws + OFF_W3;
    float* wq      = ws + OFF_WQ;
    float* az      = ws + OFF_AZ;
    float* ar      = ws + OFF_AR;
    float* ah      = ws + OFF_AH;
    float* preVexp = ws + OFF_PREV;
    float* expsum  = ws + OFF_ES;
    float* ET      = ws + OFF_ET;

    bool use_transpose = ws_size >= WS_END * sizeof(float);

    if (use_transpose) {
        dim3 tg(VOCABN / 32, HD / 32), tb(32, 8);
        k_transpose<<<tg, tb, 0, stream>>>(E_bu, ET);
        k_xe_t<<<NNODE, HD, 0, stream>>>(x_word, x_index, ET, xe);
    } else {
        k_xe<<<NNODE, HD, 0, stream>>>(x_word, x_index, E_bu, xe);
    }
    k_leaf<<<NLEAF, HD, 0, stream>>>(xe, W_z, b_z, W_h, b_h, node_h);
    k_fuse<<<512, HD, 0, stream>>>(WV, U_z, U_r, U_h, w3);
    k_ppre<<<NPAR, HD, 0, stream>>>(xe, WQ, WK, W_z, b_z, W_r, b_r, W_h, b_h,
                                    wq, az, ar, ah);
    k_chpre<<<NPAR, HD, 0, stream>>>(tree, node_h, w3, wq, preVexp, expsum);
    k_seq<<<1, 1024, 0, stream>>>(ws, W_out, b_out, y, (float*)d_out);
}

// Round 10
// 3664.159 us; speedup vs baseline: 1.0642x; 1.0642x over previous
//
#include <hip/hip_runtime.h>
#include <math.h>

#define HD 128
#define LW 32
#define VOCABN 200000
#define NLEAF 2048
#define NPAR 2047
#define NNODE 4095
#define MAXC 4
#define NCLASS 4
#define SCALE 0.08838834764831845f  // 1/sqrt(128)

// Workspace layout (floats), compile-time offsets => k_seq needs ONE base ptr
#define OFF_XE   0
#define OFF_NODE 524160    // + NNODE*HD
#define OFF_W3   786304    // + NLEAF*HD
#define OFF_WQ   851840    // + 512*HD
#define OFF_AZ   1113856   // + NPAR*HD
#define OFF_AR   1375872
#define OFF_AH   1637888
#define OFF_PREV 1899904
#define OFF_ES   2685952   // + NPAR*384
#define OFF_HG   2688000   // unused by k_seq now; layout kept stable
#define OFF_HTR  2688128
#define OFF_ET   2688256
#define WS_END   (OFF_ET + (size_t)VOCABN * HD)

// LDS-only barrier: lgkmcnt(0) makes ds_writes visible, does NOT drain vmcnt
// (prefetch global loads stay in flight across it).
#define BARL() asm volatile("s_waitcnt lgkmcnt(0)\n\ts_barrier" ::: "memory")
// Pin float4 into VGPRs component-wise (keep-alive; exact round-3 scheme).
#define PIN4(v) asm volatile("" : "+v"((v).x), "+v"((v).y), "+v"((v).z), "+v"((v).w))
#define LD4(p, k) (*(const float4*)((p) + 4 * (k)))

#define PIN_ALL() do { PIN4(A0); PIN4(A1); PIN4(A2); PIN4(A3); \
    PIN4(A4); PIN4(A5); PIN4(A6); PIN4(A7); PIN4(A8); PIN4(A9); \
    PIN4(A10); PIN4(A11); PIN4(A12); PIN4(A13); PIN4(A14); PIN4(A15); } while (0)

#define RL(x, j) __int_as_float(__builtin_amdgcn_readlane((x), (j)))

// 4 shared scalars feed TWO rows (A-row via WA regs, B-row via WB regs).
// SESSION RECORD (rounds 0-9): this readlane-broadcast + 2-row-sharing
// structure is the measured optimum. Falsified alternatives: L2-scalar
// broadcast (R0, latency), LDS b128 broadcast (R1, RF delivery), full-wave
// redundant gates (R2, issue), VGPR-resident weights (R6 spill / R8
// neutral), LDS-streamed weights (R7, LDS pipe narrower than pipelined L2),
// batched readlanes (R9, no hazard effect). Do not revisit without disasm.
#define CH2(WA, WB, XS, J) { \
    float s0_ = RL(XS, (J) + 0), s1_ = RL(XS, (J) + 1); \
    float s2_ = RL(XS, (J) + 2), s3_ = RL(XS, (J) + 3); \
    a0 += (WA).x * s0_ + (WA).y * s1_; a1 += (WA).z * s2_ + (WA).w * s3_; \
    b0 += (WB).x * s0_ + (WB).y * s1_; b1 += (WB).z * s2_ + (WB).w * s3_; }

// 2-row x 32-K matvec: 32 readlanes (compile-time lanes BASE..BASE+31), 64 FMA
#define MATVEC2(XS, BASE) do { \
    CH2(A0, A8,  XS, (BASE) + 0)  CH2(A1, A9,  XS, (BASE) + 4)  \
    CH2(A2, A10, XS, (BASE) + 8)  CH2(A3, A11, XS, (BASE) + 12) \
    CH2(A4, A12, XS, (BASE) + 16) CH2(A5, A13, XS, (BASE) + 20) \
    CH2(A6, A14, XS, (BASE) + 24) CH2(A7, A15, XS, (BASE) + 28) } while (0)

// ---------------------------------------------------------------------------
// Kernel 1a (fallback): xe via uncoalesced gather
// ---------------------------------------------------------------------------
__global__ void k_xe(const float* __restrict__ xw, const int* __restrict__ xi,
                     const float* __restrict__ E, float* __restrict__ xe) {
    int n = blockIdx.x;
    int h = threadIdx.x;
    __shared__ int   sidx[LW];
    __shared__ float sw[LW];
    if (h < LW) { sidx[h] = xi[n * LW + h]; sw[h] = xw[n * LW + h]; }
    __syncthreads();
    float acc = 0.f;
#pragma unroll
    for (int l = 0; l < LW; ++l)
        acc += E[(size_t)h * VOCABN + sidx[l]] * sw[l];
    xe[(size_t)n * HD + h] = acc;
}

// ---------------------------------------------------------------------------
// Kernel 1b: transpose E (H x VOCAB) -> ET (VOCAB x H)
// ---------------------------------------------------------------------------
__global__ void k_transpose(const float* __restrict__ E, float* __restrict__ ET) {
    __shared__ float tile[32][33];
    int vb = blockIdx.x * 32, hb = blockIdx.y * 32;
    int tx = threadIdx.x, ty = threadIdx.y;  // 32 x 8
#pragma unroll
    for (int r = 0; r < 32; r += 8)
        tile[ty + r][tx] = E[(size_t)(hb + ty + r) * VOCABN + vb + tx];
    __syncthreads();
#pragma unroll
    for (int r = 0; r < 32; r += 8)
        ET[(size_t)(vb + ty + r) * HD + hb + tx] = tile[tx][ty + r];
}

// Kernel 1c: coalesced gather+reduce from ET.
__global__ void k_xe_t(const float* __restrict__ xw, const int* __restrict__ xi,
                       const float* __restrict__ ET, float* __restrict__ xe) {
    int n = blockIdx.x;
    int h = threadIdx.x;
    __shared__ int   sidx[LW];
    __shared__ float sw[LW];
    if (h < LW) { sidx[h] = xi[n * LW + h]; sw[h] = xw[n * LW + h]; }
    __syncthreads();
    float acc = 0.f;
#pragma unroll
    for (int l = 0; l < LW; ++l)
        acc += ET[(size_t)sidx[l] * HD + h] * sw[l];
    xe[(size_t)n * HD + h] = acc;
}

// ---------------------------------------------------------------------------
// Kernel 2: leaf cells -> node_h[0:NLEAF]
// ---------------------------------------------------------------------------
__global__ void k_leaf(const float* __restrict__ xe, const float* __restrict__ Wz,
                       const float* __restrict__ bz, const float* __restrict__ Wh,
                       const float* __restrict__ bh, float* __restrict__ node_h) {
    int n = blockIdx.x;
    int j = threadIdx.x;
    __shared__ float xl[HD];
    xl[j] = xe[(size_t)n * HD + j];
    __syncthreads();
    float az = bz[j], ah = bh[j];
    const float* wzr = Wz + (size_t)j * HD;
    const float* whr = Wh + (size_t)j * HD;
#pragma unroll 4
    for (int k = 0; k < HD; ++k) { az += wzr[k] * xl[k]; ah += whr[k] * xl[k]; }
    float z = 1.f / (1.f + expf(-az));
    float c = tanhf(ah);
    node_h[(size_t)n * HD + j] = (1.f - z) * c;
}

// ---------------------------------------------------------------------------
// Kernel 3: fused weight stack W3 (512 x 128):
//   rows 0..127: WV^T / 128..255: U_z WV^T / 256..383: U_r WV^T / 384..511: U_h
// ---------------------------------------------------------------------------
__global__ void k_fuse(const float* __restrict__ WV, const float* __restrict__ Uz,
                       const float* __restrict__ Ur, const float* __restrict__ Uh,
                       float* __restrict__ w3) {
    int r = blockIdx.x;
    int b = threadIdx.x;
    float v;
    if (r < 128) {
        v = WV[(size_t)b * HD + r];
    } else if (r < 384) {
        const float* u  = (r < 256 ? Uz + (size_t)(r - 128) * HD : Ur + (size_t)(r - 256) * HD);
        const float* wv = WV + (size_t)b * HD;
        float a = 0.f;
#pragma unroll 4
        for (int j = 0; j < HD; ++j) a += u[j] * wv[j];
        v = a;
    } else {
        v = Uh[(size_t)(r - 384) * HD + b];
    }
    w3[(size_t)r * HD + b] = v;
}

// ---------------------------------------------------------------------------
// Kernel 4: per-parent precompute
// ---------------------------------------------------------------------------
__global__ void k_ppre(const float* __restrict__ xe, const float* __restrict__ WQ,
                       const float* __restrict__ WK, const float* __restrict__ Wz,
                       const float* __restrict__ bz, const float* __restrict__ Wr,
                       const float* __restrict__ br, const float* __restrict__ Wh,
                       const float* __restrict__ bh, float* __restrict__ wq,
                       float* __restrict__ az, float* __restrict__ ar,
                       float* __restrict__ ah) {
    int i = blockIdx.x;
    int j = threadIdx.x;
    __shared__ float xl[HD], ql[HD];
    xl[j] = xe[(size_t)(NLEAF + i) * HD + j];
    __syncthreads();
    float q = 0.f;
#pragma unroll 4
    for (int h = 0; h < HD; ++h) q += xl[h] * WQ[(size_t)h * HD + j];
    ql[j] = 1.f / (1.f + expf(-q));
    __syncthreads();
    float w = 0.f;
#pragma unroll 4
    for (int k = 0; k < HD; ++k) w += WK[(size_t)j * HD + k] * ql[k];
    wq[(size_t)i * HD + j] = w;
    float vz = bz[j], vr = br[j], vh = bh[j];
#pragma unroll 4
    for (int k = 0; k < HD; ++k) {
        float xv = xl[k];
        vz += Wz[(size_t)j * HD + k] * xv;
        vr += Wr[(size_t)j * HD + k] * xv;
        vh += Wh[(size_t)j * HD + k] * xv;
    }
    az[(size_t)i * HD + j] = vz;
    ar[(size_t)i * HD + j] = vr;
    ah[(size_t)i * HD + j] = vh;
}

// ---------------------------------------------------------------------------
// Kernel 5: aggregated leaf-child precompute per parent
// ---------------------------------------------------------------------------
__global__ void k_chpre(const int* __restrict__ tree, const float* __restrict__ node_h,
                        const float* __restrict__ w3, const float* __restrict__ wq_all,
                        float* __restrict__ preVexp, float* __restrict__ expsum) {
    int i = blockIdx.x;
    int j = threadIdx.x;
    __shared__ float hl[HD];
    __shared__ float red[HD];
    float wqj = wq_all[(size_t)i * HD + j];
    float acc0 = 0.f, acc1 = 0.f, acc2 = 0.f, esum = 0.f;
    for (int c = 0; c < MAXC; ++c) {
        int child = tree[i * MAXC + c];
        if (child < 0 || child >= NLEAF) continue;  // uniform per block
        __syncthreads();
        hl[j] = node_h[(size_t)child * HD + j];
        __syncthreads();
        red[j] = hl[j] * wqj;
        __syncthreads();
        for (int s = 64; s > 0; s >>= 1) {
            if (j < s) red[j] += red[j + s];
            __syncthreads();
        }
        float e = expf(red[0] * SCALE);
        float d0 = 0.f, d1 = 0.f, d2 = 0.f;
#pragma unroll 4
        for (int k = 0; k < HD; ++k) {
            float x = hl[k];
            d0 += w3[(size_t)j * HD + k] * x;
            d1 += w3[(size_t)(128 + j) * HD + k] * x;
            d2 += w3[(size_t)(256 + j) * HD + k] * x;
        }
        acc0 += e * d0; acc1 += e * d1; acc2 += e * d2; esum += e;
    }
    preVexp[(size_t)i * 384 + j]       = acc0;
    preVexp[(size_t)i * 384 + 128 + j] = acc1;
    preVexp[(size_t)i * 384 + 256 + j] = acc2;
    if (j == 0) expsum[i] = esum;
}

// ---------------------------------------------------------------------------
// Kernel 6: sequential chain. 1024 threads (16 waves, 4/EU). ROUND-3
// configuration restored verbatim -- the measured optimum of this structure
// (k_seq 3236 us). Lane-local h, no global stores / dcache_inv / vmcnt
// drains; 2-rows-x-32K matvecs (32 readlanes shared by 2 rows); gates only
// on the 4 P3 waves; 3 phases / 3 LDS-only barriers per step.
// Wave roles (wave w, SIMD = w&3):
//   w<12 (P1): K-chunk c1=w&3, row-group g1=w>>2; rows 128g1+l, 128g1+64+l
//   w>=12 (P3): K-chunk c3=w-12; U_h rows l, 64+l; gates for m3=64*(c3>>1)+l
// ---------------------------------------------------------------------------
__global__ __launch_bounds__(1024)
__attribute__((amdgpu_waves_per_eu(4, 4)))
void k_seq(float* __restrict__ ws, const float* __restrict__ Wout,
           const float* __restrict__ bout, const float* __restrict__ y,
           float* __restrict__ out) {
    const int t  = threadIdx.x;
    const int l  = t & 63;
    const int w  = t >> 6;               // wave 0..15
    const bool isP1 = (w < 12);
    // P1 mapping
    const int c1 = w & 3;                // K-chunk (32 floats)
    const int g1 = w >> 2;               // row group 0..2
    const int r0 = 128 * g1 + l;         // rows r0 and r0+64
    // P3 mapping
    const int w12 = w - 12;
    const int c3  = w12 & 3;             // K-chunk
    const int q3  = c3 >> 1;             // m-half
    const int m3  = 64 * q3 + l;         // elementwise lane (P3 only)

    __shared__ float part1[4 * 384];     // [chunk][row]
    __shared__ float part3[4 * 128];     // [chunk][row]
    __shared__ float red[HD];            // h*wq products (for next score)
    __shared__ float sS;                 // reduced chain score * SCALE
    __shared__ float h_lds[HD];
    __shared__ float outv[NCLASS];

    // ---- weights: 16 pinned float4 per thread (2 rows x 32-K chunk) ----
    const int woff = isP1 ? (r0 * HD + 32 * c1)
                          : ((384 + l) * HD + 32 * c3);
    const float* wp0 = ws + OFF_W3 + woff;
    const float* wp1 = wp0 + 64 * HD;    // row +64
    float4 A0 = LD4(wp0, 0), A1 = LD4(wp0, 1), A2 = LD4(wp0, 2), A3 = LD4(wp0, 3),
           A4 = LD4(wp0, 4), A5 = LD4(wp0, 5), A6 = LD4(wp0, 6), A7 = LD4(wp0, 7),
           A8 = LD4(wp1, 0), A9 = LD4(wp1, 1), A10 = LD4(wp1, 2), A11 = LD4(wp1, 3),
           A12 = LD4(wp1, 4), A13 = LD4(wp1, 5), A14 = LD4(wp1, 6), A15 = LD4(wp1, 7);
    PIN_ALL();

    // ---- prefetch registers (P3 waves only; element m3) ----
    float pv0 = 0.f, pv1 = 0.f, pv2 = 0.f, paz = 0.f, par = 0.f, pah = 0.f,
          pwq = 0.f, pes = 0.f;
    if (!isP1) {
        pv0 = ws[OFF_PREV + m3];       pv1 = ws[OFF_PREV + 128 + m3];
        pv2 = ws[OFF_PREV + 256 + m3];
        paz = ws[OFF_AZ + m3];         par = ws[OFF_AR + m3];
        pah = ws[OFF_AH + m3];
        pes = ws[OFF_ES];
        pwq = ws[OFF_WQ + HD + m3];    // wq[1], consumed in phase C of step 0
    }
    if (t < HD) {
        h_lds[t] = 0.f;                          // h_{-1} = 0
        red[t]   = (t < 64) ? -1e30f : 0.f;      // step 0: no chain child
    }
    __syncthreads();

    float zreg = 0.f, htvreg = 0.f;

    for (int i = 0; i < NPAR; ++i) {
        const int inext = (i + 1 < NPAR) ? i + 1 : NPAR - 1;
        const int in2   = (i + 2 < NPAR) ? i + 2 : NPAR - 1;

        PIN_ALL();

        // ---- Phase A: P1 matvec. h fetched via ONE per-lane ds_read with
        //      half-wave duplication so readlane indices are literal 0..31.
        //      Wave 12 reduces the chain score concurrently. ----
        if (isP1) {
            const int hx = __float_as_int(h_lds[32 * c1 + (l & 31)]);
            float a0 = 0.f, a1 = 0.f, b0 = 0.f, b1 = 0.f;
            MATVEC2(hx, 0);
            part1[c1 * 384 + r0]      = a0 + a1;
            part1[c1 * 384 + r0 + 64] = b0 + b1;
        } else if (w12 == 0) {
            float s = red[l] + red[l + 64];
#pragma unroll
            for (int o = 32; o > 0; o >>= 1) s += __shfl_down(s, o, 64);
            if (l == 0) sS = s * SCALE;
        }
        BARL();

        // ---- Phase B: P3 waves only: gates for element m3, then 2x32 U_h
        //      matvec on htr (in-lane; readlane base picked by chunk half) ----
        if (!isP1) {
            float e   = expf(sS);
            float vd  = part1[m3]        + part1[384 + m3]
                      + part1[768 + m3]  + part1[1152 + m3];
            float zd  = part1[128 + m3]  + part1[512 + m3]
                      + part1[896 + m3]  + part1[1280 + m3];
            float rd  = part1[256 + m3]  + part1[640 + m3]
                      + part1[1024 + m3] + part1[1408 + m3];
            float inv = 1.f / (pes + e);
            float htv = (pv0 + e * vd) * inv;
            float z   = 1.f / (1.f + expf(-(paz + (pv1 + e * zd) * inv)));
            float rr  = 1.f / (1.f + expf(-(par + (pv2 + e * rd) * inv)));
            float htr = htv * rr;
            zreg = z; htvreg = htv;
            const int xh = __float_as_int(htr);
            float a0 = 0.f, a1 = 0.f, b0 = 0.f, b1 = 0.f;
            if ((c3 & 1) == 0) { MATVEC2(xh, 0); } else { MATVEC2(xh, 32); }
            part3[c3 * 128 + l]      = a0 + a1;
            part3[c3 * 128 + l + 64] = b0 + b1;
        }
        BARL();

        // ---- Phase C: P3 waves: finalize h[m3]; publish h + score products;
        //      refill prefetches (fire-and-forget) ----
        if (!isP1) {
            float u  = part3[m3]       + part3[128 + m3]
                     + part3[256 + m3] + part3[384 + m3];
            float c  = tanhf(pah + u);
            float hv = zreg * htvreg + (1.f - zreg) * c;
            if ((w12 & 1) == 0) {       // one wave per half: w12=0 (q0), 2 (q1)
                h_lds[m3] = hv;
                red[m3]   = hv * pwq;   // <h_i, wq_{i+1}> products
            }
            pv0 = ws[OFF_PREV + inext * 384 + m3];
            pv1 = ws[OFF_PREV + inext * 384 + 128 + m3];
            pv2 = ws[OFF_PREV + inext * 384 + 256 + m3];
            paz = ws[OFF_AZ + inext * HD + m3];
            par = ws[OFF_AR + inext * HD + m3];
            pah = ws[OFF_AH + inext * HD + m3];
            pes = ws[OFF_ES + inext];
            pwq = ws[OFF_WQ + in2 * HD + m3];
        }
        BARL();
    }

    // ---- output head (h_lds holds h_{NPAR-1}) ----
    if (t < NCLASS) {
        float acc = bout[t];
#pragma unroll 4
        for (int k = 0; k < HD; ++k) acc += Wout[(size_t)t * HD + k] * h_lds[k];
        outv[t] = acc;
    }
    __syncthreads();
    if (t == 0) {
        float mx = fmaxf(fmaxf(outv[0], outv[1]), fmaxf(outv[2], outv[3]));
        float e0 = expf(outv[0] - mx), e1 = expf(outv[1] - mx);
        float e2 = expf(outv[2] - mx), e3 = expf(outv[3] - mx);
        float inv = 1.f / (e0 + e1 + e2 + e3);
        float p0 = e0 * inv, p1 = e1 * inv, p2 = e2 * inv, p3 = e3 * inv;
        out[0] = p0; out[1] = p1; out[2] = p2; out[3] = p3;
        float d0 = y[0] - p0, d1 = y[1] - p1, d2 = y[2] - p2, d3 = y[3] - p3;
        out[4] = d0 * d0 + d1 * d1 + d2 * d2 + d3 * d3;
    }
}

// ---------------------------------------------------------------------------
extern "C" void kernel_launch(void* const* d_in, const int* in_sizes, int n_in,
                              void* d_out, int out_size, void* d_ws, size_t ws_size,
                              hipStream_t stream) {
    const float* x_word  = (const float*)d_in[0];
    const int*   x_index = (const int*)d_in[1];
    const int*   tree    = (const int*)d_in[2];
    const float* y       = (const float*)d_in[3];
    const float* E_bu    = (const float*)d_in[4];
    const float* WQ      = (const float*)d_in[5];
    const float* WK      = (const float*)d_in[6];
    const float* WV      = (const float*)d_in[7];
    const float* W_z     = (const float*)d_in[8];
    const float* U_z     = (const float*)d_in[9];
    const float* b_z     = (const float*)d_in[10];
    const float* W_r     = (const float*)d_in[11];
    const float* U_r     = (const float*)d_in[12];
    const float* b_r     = (const float*)d_in[13];
    const float* W_h     = (const float*)d_in[14];
    const float* U_h     = (const float*)d_in[15];
    const float* b_h     = (const float*)d_in[16];
    const float* W_out   = (const float*)d_in[17];
    const float* b_out   = (const float*)d_in[18];

    float* ws      = (float*)d_ws;
    float* xe      = ws + OFF_XE;
    float* node_h  = ws + OFF_NODE;
    float* w3      = ws + OFF_W3;
    float* wq      = ws + OFF_WQ;
    float* az      = ws + OFF_AZ;
    float* ar      = ws + OFF_AR;
    float* ah      = ws + OFF_AH;
    float* preVexp = ws + OFF_PREV;
    float* expsum  = ws + OFF_ES;
    float* ET      = ws + OFF_ET;

    bool use_transpose = ws_size >= WS_END * sizeof(float);

    if (use_transpose) {
        dim3 tg(VOCABN / 32, HD / 32), tb(32, 8);
        k_transpose<<<tg, tb, 0, stream>>>(E_bu, ET);
        k_xe_t<<<NNODE, HD, 0, stream>>>(x_word, x_index, ET, xe);
    } else {
        k_xe<<<NNODE, HD, 0, stream>>>(x_word, x_index, E_bu, xe);
    }
    k_leaf<<<NLEAF, HD, 0, stream>>>(xe, W_z, b_z, W_h, b_h, node_h);
    k_fuse<<<512, HD, 0, stream>>>(WV, U_z, U_r, U_h, w3);
    k_ppre<<<NPAR, HD, 0, stream>>>(xe, WQ, WK, W_z, b_z, W_r, b_r, W_h, b_h,
                                    wq, az, ar, ah);
    k_chpre<<<NPAR, HD, 0, stream>>>(tree, node_h, w3, wq, preVexp, expsum);
    k_seq<<<1, 1024, 0, stream>>>(ws, W_out, b_out, y, (float*)d_out);
}